// Round 11
// baseline (477.539 us; speedup 1.0000x reference)
//
#include <hip/hip_runtime.h>
#include <stdint.h>

// Problem constants
constexpr int B_ = 8, N_ = 4096, E_ = 2048, C_ = 128;
constexpr int KT  = 32;    // K per MFMA step
constexpr int MT  = 64;    // M rows per block (4 x 16-row groups, all owned by every wave)
constexpr int LRP = 65;    // reduction LDS row stride (floats, +1 pad)
constexpr int PACK_BLKS = 2048;  // 8 batches x 128 n-groups x 2 e-halves

typedef short bf16x8 __attribute__((ext_vector_type(8)));
typedef float f32x4  __attribute__((ext_vector_type(4)));
typedef unsigned int u32x4 __attribute__((ext_vector_type(4)));

__device__ inline uint16_t bf16_rne(float f) {
    uint32_t u = __builtin_bit_cast(uint32_t, f);
    return (uint16_t)((u + 0x7FFFu + ((u >> 16) & 1u)) >> 16);
}

constexpr size_t BIT_B = (size_t)(N_ / 32) * E_;       // 262144 dwords per batch
constexpr size_t HT_E  = (size_t)B_ * BIT_B;           // 2M dwords = 8 MB
constexpr size_t EBF_E = (size_t)B_ * C_ * E_;         // 2M bf16 = 4 MB
constexpr size_t RS_E  = (size_t)B_ * E_;              // 16K floats
constexpr size_t RD_E  = (size_t)B_ * N_;              // 32K floats

// ---------------------------------------------------------------------------
// 2x2-SPLIT MFMA GEMM (MODE 1/2) and N-split fc (MODE 0).
//  MODE 0 (fc) : A = x fp32, B = W f32 converted on the fly (no WTb dep!),
//                N-split (wave owns 2 col-tiles, full K=128, 2-deep, no LDS),
//                out bf16 C^T xwbT (+bias).
//  MODE 1 (v2e): A = HT bits (2.0),  B = xwbT, out bf16 C^T ebfT (x 0.5/s_e)
//  MODE 2 (e2v): A = HTe bits (2.0), B = ebfT, out fp32 row-major (x 0.5/d_n)
// MODE 1/2: wave = (k-half, col-half), 4 col-tiles x K/2, 4-deep named-register
// B pipeline (compiler-scoreboarded waits), ONE-barrier LDS k-half reduction.
// ---------------------------------------------------------------------------

#define LOADA(S, k0_) do {                                                            \
    if constexpr (MODE == 0) {                                                        \
        _Pragma("unroll")                                                             \
        for (int g = 0; g < NG; ++g) {                                                \
            const float* ap = Ax + ((size_t)batch * N_ + m0 + g * 16 + l15) * C_ + (k0_) + quad * 8; \
            const float4 f0 = *(const float4*)ap;                                     \
            const float4 f1 = *(const float4*)(ap + 4);                               \
            af##S[g*8+0]=f0.x; af##S[g*8+1]=f0.y; af##S[g*8+2]=f0.z; af##S[g*8+3]=f0.w; \
            af##S[g*8+4]=f1.x; af##S[g*8+5]=f1.y; af##S[g*8+6]=f1.z; af##S[g*8+7]=f1.w; \
        }                                                                             \
    } else {                                                                          \
        const uint32_t* p = Hp + (size_t)((k0_) >> 5) * RL + m0 + l15;                \
        _Pragma("unroll")                                                             \
        for (int g = 0; g < NG; ++g) aw##S[g] = p[g * 16];                            \
    } } while (0)

#define LOADB(S, k0_) do {                                                            \
    if constexpr (MODE == 0) {                                                        \
        _Pragma("unroll")                                                             \
        for (int j2 = 0; j2 < NJWm; ++j2) {                                           \
            const int c = (jw + j2) * 16 + l15;                                       \
            _Pragma("unroll")                                                         \
            for (int jj = 0; jj < 8; ++jj)                                            \
                bq##S[j2][jj] = (short)bf16_rne(Wf[(size_t)((k0_) + quad * 8 + jj) * C_ + c]); \
        }                                                                             \
    } else {                                                                          \
        _Pragma("unroll")                                                             \
        for (int j2 = 0; j2 < NJWm; ++j2)                                             \
            bq##S[j2] = *(const bf16x8*)&Bp[(size_t)((jw + j2) * 16 + l15) * K + (k0_) + quad * 8]; \
    } } while (0)

// bit->bf16(2.0) fast expansion: nibble * 0x204081 spreads bit i to byte i;
// &0x01010101 <<6 makes bytes 0x40*bit; v_perm zero-interleaves -> packed
// bf16 pairs. 12 VALU per 8 elements (vs ~64 naive, R7 ablation evidence).
#define MKFRAGS(S, A)                                                                 \
    bf16x8 A[NG];                                                                     \
    do {                                                                              \
    if constexpr (MODE == 0) {                                                        \
        _Pragma("unroll")                                                             \
        for (int g = 0; g < NG; ++g)                                                  \
            { _Pragma("unroll")                                                       \
              for (int jj = 0; jj < 8; ++jj) A[g][jj] = (short)bf16_rne(af##S[g*8+jj]); } \
    } else {                                                                          \
        const int qs = quad * 8;                                                      \
        _Pragma("unroll")                                                             \
        for (int g = 0; g < NG; ++g) {                                                \
            const uint32_t wv = aw##S[g];                                             \
            const uint32_t nb0 = (wv >> qs) & 0xFu;                                   \
            const uint32_t nb1 = (wv >> (qs + 4)) & 0xFu;                             \
            const uint32_t s0m = ((nb0 * 0x204081u) & 0x01010101u) << 6;              \
            const uint32_t s1m = ((nb1 * 0x204081u) & 0x01010101u) << 6;              \
            u32x4 qq = { __builtin_amdgcn_perm(s0m, 0u, 0x05000400u),                 \
                         __builtin_amdgcn_perm(s0m, 0u, 0x07000600u),                 \
                         __builtin_amdgcn_perm(s1m, 0u, 0x05000400u),                 \
                         __builtin_amdgcn_perm(s1m, 0u, 0x07000600u) };               \
            A[g] = __builtin_bit_cast(bf16x8, qq);                                    \
        }                                                                             \
    } } while (0)

template <int MODE>
__device__ __attribute__((always_inline))
void gemm_body(int bid, const float* __restrict__ Ax, const uint32_t* __restrict__ bits,
               const uint16_t* __restrict__ Btb, const float* __restrict__ Wf,
               const float* __restrict__ bias, const float* __restrict__ rcp,
               uint16_t* __restrict__ outT, float* __restrict__ outF) {
    constexpr int K    = (MODE == 0) ? C_ : (MODE == 1) ? N_ : E_;
    constexpr int NJWm = (MODE == 0) ? 2 : 4;     // col-tiles per wave
    constexpr int KH   = (MODE == 0) ? K : K / 2; // per-wave K span
    constexpr int SW   = KH / KT;                 // 4 / 64 / 32 steps
    constexpr int OLD  = (MODE == 0) ? N_ : E_;
    constexpr int RL   = (MODE == 1) ? E_ : N_;   // bit-row stride == rcp stride
    constexpr int NG   = MT / 16;                 // 4 m-groups per wave

    __shared__ float R[(MODE == 0) ? 1 : (2 * 64 * LRP)];

    const int t = threadIdx.x, wave = t >> 6, lane = t & 63;
    const int l15 = lane & 15, quad = lane >> 4;
    const int kh = (MODE == 0) ? 0 : (wave & 1);  // k-half
    const int jg = (MODE == 0) ? wave : (wave >> 1);
    const int jw = jg * NJWm;                     // first owned col-tile
    const int kwv = kh * KH;
    const int batch = bid & 7;                    // batch -> XCD: panel stays in one L2
    const int m0 = (bid >> 3) * MT;

    const uint16_t* Bp = Btb + (MODE == 0 ? (size_t)0 : (size_t)batch * C_ * K);
    const uint32_t* Hp = bits + (size_t)batch * BIT_B;

    f32x4 acc[NG * NJWm];
    // all pipeline-stage names declared for every MODE (constexpr-discarded
    // branches still require name lookup -- R9 lesson); unused = free
    float    af0[NG * 8], af1[NG * 8], af2[NG * 8], af3[NG * 8];
    uint32_t aw0[NG], aw1[NG], aw2[NG], aw3[NG];
    bf16x8   bq0[NJWm], bq1[NJWm], bq2[NJWm], bq3[NJWm];

    auto mfma_all = [&](const bf16x8 (&A)[NG], const bf16x8 (&bv)[NJWm])
        __attribute__((always_inline)) {
#pragma unroll
        for (int j2 = 0; j2 < NJWm; ++j2)
#pragma unroll
            for (int g = 0; g < NG; ++g)
                acc[g * NJWm + j2] = __builtin_amdgcn_mfma_f32_16x16x32_bf16(A[g], bv[j2], acc[g * NJWm + j2], 0, 0, 0);
    };

#pragma unroll
    for (int i = 0; i < NG * NJWm; ++i) acc[i] = (f32x4){0.f, 0.f, 0.f, 0.f};

    if constexpr (MODE == 0) {
        // fc: N-split full-K, 2-deep register pipeline, no LDS, no barrier
        LOADA(0, 0);  LOADB(0, 0);
        LOADA(1, KT); LOADB(1, KT);
        { MKFRAGS(0, A0); mfma_all(A0, bq0); LOADA(0, 2 * KT); LOADB(0, 2 * KT); }
        { MKFRAGS(1, A1); mfma_all(A1, bq1); LOADA(1, 3 * KT); LOADB(1, 3 * KT); }
        { MKFRAGS(0, A0); mfma_all(A0, bq0); }
        { MKFRAGS(1, A1); mfma_all(A1, bq1); }
    } else {
        // 4-deep register pipeline (3-step prefetch lead)
        LOADA(0, kwv);          LOADB(0, kwv);
        LOADA(1, kwv + KT);     LOADB(1, kwv + KT);
        LOADA(2, kwv + 2 * KT); LOADB(2, kwv + 2 * KT);
        LOADA(3, kwv + 3 * KT); LOADB(3, kwv + 3 * KT);
#pragma unroll 1
        for (int s = 0; s < SW - 4; s += 4) {
            { MKFRAGS(0, A0); mfma_all(A0, bq0); LOADA(0, kwv + (s + 4) * KT); LOADB(0, kwv + (s + 4) * KT); }
            { MKFRAGS(1, A1); mfma_all(A1, bq1); LOADA(1, kwv + (s + 5) * KT); LOADB(1, kwv + (s + 5) * KT); }
            { MKFRAGS(2, A2); mfma_all(A2, bq2); LOADA(2, kwv + (s + 6) * KT); LOADB(2, kwv + (s + 6) * KT); }
            { MKFRAGS(3, A3); mfma_all(A3, bq3); LOADA(3, kwv + (s + 7) * KT); LOADB(3, kwv + (s + 7) * KT); }
        }
        { MKFRAGS(0, A0); mfma_all(A0, bq0); }
        { MKFRAGS(1, A1); mfma_all(A1, bq1); }
        { MKFRAGS(2, A2); mfma_all(A2, bq2); }
        { MKFRAGS(3, A3); mfma_all(A3, bq3); }

        // ---- k-half reduction: ONE barrier ----
        const int rbase = jg * 64 * LRP;
        if (kh == 1) {
#pragma unroll
            for (int g = 0; g < NG; ++g)
#pragma unroll
                for (int j2 = 0; j2 < NJWm; ++j2)
#pragma unroll
                    for (int r = 0; r < 4; ++r)
                        R[rbase + (g * 16 + quad * 4 + r) * LRP + j2 * 16 + l15] = acc[g * NJWm + j2][r];
        }
        __syncthreads();
        if (kh != 0) return;
#pragma unroll
        for (int g = 0; g < NG; ++g)
#pragma unroll
            for (int j2 = 0; j2 < NJWm; ++j2)
#pragma unroll
                for (int r = 0; r < 4; ++r)
                    acc[g * NJWm + j2][r] += R[rbase + (g * 16 + quad * 4 + r) * LRP + j2 * 16 + l15];
    }

    // ---- epilogue (MODE 0: all 4 waves; MODE 1/2: waves 0,2 = col-halves) ----
    float mul[NG][4];
    if constexpr (MODE != 0) {
#pragma unroll
        for (int g = 0; g < NG; ++g) {
            const float4 rv = *(const float4*)&rcp[(size_t)batch * RL + m0 + g * 16 + quad * 4];
            mul[g][0] = rv.x; mul[g][1] = rv.y; mul[g][2] = rv.z; mul[g][3] = rv.w;
        }
    }
#pragma unroll
    for (int g = 0; g < NG; ++g) {
        const int row = m0 + g * 16 + quad * 4;
        if constexpr (MODE == 2) {
            float* op = outF + ((size_t)batch * N_ + row) * C_;
#pragma unroll
            for (int j2 = 0; j2 < NJWm; ++j2) {
                const int c = (jw + j2) * 16 + l15;
#pragma unroll
                for (int r = 0; r < 4; ++r) op[(size_t)r * C_ + c] = acc[g * NJWm + j2][r] * mul[g][r];
            }
        } else {
#pragma unroll
            for (int j2 = 0; j2 < NJWm; ++j2) {
                const int c = (jw + j2) * 16 + l15;
                float v0, v1, v2, v3;
                if constexpr (MODE == 0) {
                    float bb = bias[c];
                    v0 = acc[g * NJWm + j2][0] + bb; v1 = acc[g * NJWm + j2][1] + bb;
                    v2 = acc[g * NJWm + j2][2] + bb; v3 = acc[g * NJWm + j2][3] + bb;
                } else {
                    v0 = acc[g * NJWm + j2][0] * mul[g][0]; v1 = acc[g * NJWm + j2][1] * mul[g][1];
                    v2 = acc[g * NJWm + j2][2] * mul[g][2]; v3 = acc[g * NJWm + j2][3] * mul[g][3];
                }
                uint32_t q0 = (uint32_t)bf16_rne(v0) | ((uint32_t)bf16_rne(v1) << 16);
                uint32_t q1 = (uint32_t)bf16_rne(v2) | ((uint32_t)bf16_rne(v3) << 16);
                uint16_t* op = outT + ((size_t)batch * C_ + c) * OLD + row;
                *(uint2*)op = make_uint2(q0, q1);
            }
        }
    }
}

// ---------------------------------------------------------------------------
// pack_fc: blocks [0,2048) pack H -> HT with float4 loads (4 e's/thread, 4x
// fewer mem instructions than R10's scalar path); blocks [2048,2560) run fc
// (independent of pack -- W/x/bias only -> hides fc's serial time under the
// HBM-bound pack phase and drops one launch).
// ---------------------------------------------------------------------------
__global__ __launch_bounds__(256, 2)
void pack_fc_k(const float* __restrict__ H, uint32_t* __restrict__ HT,
               const float* __restrict__ x, const float* __restrict__ W,
               const float* __restrict__ bias, uint16_t* __restrict__ xwbT) {
    if (blockIdx.x >= PACK_BLKS) {
        gemm_body<0>(blockIdx.x - PACK_BLKS, x, nullptr, nullptr, W, bias, nullptr, xwbT, nullptr);
        return;
    }
    const int t  = threadIdx.x;
    const int eg = blockIdx.x & 1;
    const int ng = (blockIdx.x >> 1) & 127;
    const int b  = blockIdx.x >> 8;
    const int e0 = eg * 1024 + t * 4;
    const float* hp = H + ((size_t)b * N_ + ng * 32) * E_ + e0;
    uint32_t w0 = 0, w1 = 0, w2 = 0, w3 = 0;
#pragma unroll
    for (int i = 0; i < 32; ++i) {
        const float4 f = *(const float4*)(hp + (size_t)i * E_);
        w0 |= (f.x > 0.5f) ? (1u << i) : 0u;
        w1 |= (f.y > 0.5f) ? (1u << i) : 0u;
        w2 |= (f.z > 0.5f) ? (1u << i) : 0u;
        w3 |= (f.w > 0.5f) ? (1u << i) : 0u;
    }
    *(uint4*)&HT[((size_t)b * (N_ / 32) + ng) * E_ + e0] = make_uint4(w0, w1, w2, w3);
}

// ---------------------------------------------------------------------------
// prep (everything derived from HT only -- no intra-kernel ordering hazard):
//  [0,256)    : rd_n = 0.5/deg(n) via per-bit ballot over HT rows (R3 method)
//  [256,320)  : rs_e = 0.5/deg(e) via popc over HT columns
//  [320,8512) : HTe[b][e/32][n] build via ballot transpose of HT words
// ---------------------------------------------------------------------------
__global__ void prep_kernel(const uint32_t* __restrict__ HT, uint32_t* __restrict__ HTe,
                            float* __restrict__ rs_e, float* __restrict__ rd_n) {
    const int blk = blockIdx.x, t = threadIdx.x;
    const int wave = t >> 6, lane = t & 63;
    if (blk < 256) {                              // rd_n: 1024 wave-tasks = (b, ng)
        const int wid = blk * 4 + wave;
        const int b = wid >> 7, ng = wid & 127;
        const uint32_t* p = HT + ((size_t)b * (N_ / 32) + ng) * E_;
        int cnt = 0;
#pragma unroll 1
        for (int c8 = 0; c8 < E_ / 64; ++c8) {
            const uint32_t w = p[c8 * 64 + lane];
#pragma unroll
            for (int i = 0; i < 32; ++i) {
                unsigned long long m = __ballot((w >> i) & 1u);
                if (lane == i) cnt += __popcll(m);
            }
        }
        if (lane < 32)
            rd_n[(size_t)b * N_ + ng * 32 + lane] = (cnt > 0) ? 0.5f / (float)cnt : 0.f;
    } else if (blk < 320) {                       // rs_e: 16384 = (b, e)
        const int i = (blk - 256) * 256 + t;
        const int b = i >> 11, e = i & 2047;
        const uint32_t* p = HT + (size_t)b * BIT_B + e;
        int s = 0;
#pragma unroll 1
        for (int ng = 0; ng < N_ / 32; ++ng) s += __popc(p[(size_t)ng * E_]);
        rs_e[i] = (s > 0) ? 0.5f / (float)s : 0.f;
    } else {                                      // HTe: 32768 wave-tasks
        const int wid = (blk - 320) * 4 + wave;   // (b, ng, eg64)
        const int b = wid >> 12, rest = wid & 4095;
        const int ng = rest >> 5, eg64 = rest & 31;
        const uint32_t w = HT[((size_t)b * (N_ / 32) + ng) * E_ + eg64 * 64 + lane];
        uint32_t val = 0;
#pragma unroll
        for (int i = 0; i < 32; ++i) {
            unsigned long long m = __ballot((w >> i) & 1u);
            uint32_t half = (lane < 32) ? (uint32_t)m : (uint32_t)(m >> 32);
            if ((lane & 31) == i) val = half;
        }
        HTe[((size_t)b * (E_ / 32) + eg64 * 2 + (lane >> 5)) * N_ + ng * 32 + (lane & 31)] = val;
    }
}

// Named wrappers -> attributable rocprof rows
__global__ __launch_bounds__(256, 2)
void v2e_k(const uint32_t* __restrict__ HT, const uint16_t* __restrict__ Btb,
           const float* __restrict__ rcp, uint16_t* __restrict__ outT) {
    gemm_body<1>(blockIdx.x, nullptr, HT, Btb, nullptr, nullptr, rcp, outT, nullptr);
}
__global__ __launch_bounds__(256, 2)
void e2v_k(const uint32_t* __restrict__ HTe, const uint16_t* __restrict__ Btb,
           const float* __restrict__ rcp, float* __restrict__ outF) {
    gemm_body<2>(blockIdx.x, nullptr, HTe, Btb, nullptr, nullptr, rcp, nullptr, outF);
}

// ---------------------------------------------------------------------------
extern "C" void kernel_launch(void* const* d_in, const int* in_sizes, int n_in,
                              void* d_out, int out_size, void* d_ws, size_t ws_size,
                              hipStream_t stream) {
    const float* x    = (const float*)d_in[0];   // [8,4096,128]
    const float* H    = (const float*)d_in[1];   // [8,4096,2048]
    const float* W    = (const float*)d_in[2];   // [128,128]
    const float* bias = (const float*)d_in[3];   // [128]
    float* out = (float*)d_out;                  // [8,4096,128]

    // ws (~20.3 MB): HT 8MB | HTe 8MB | ebfT 4MB | rs_e 64KB | rd_n 128KB
    uint32_t* HT   = (uint32_t*)d_ws;
    uint32_t* HTe  = HT + HT_E;
    uint16_t* ebfT = (uint16_t*)(HTe + HT_E);
    float*    rs_e = (float*)(ebfT + EBF_E);
    float*    rd_n = rs_e + RS_E;
    uint16_t* xwbT = (uint16_t*)d_out;           // d_out is dead scratch until e2v

    pack_fc_k<<<dim3(PACK_BLKS + 8 * (N_ / MT)), dim3(256), 0, stream>>>(H, HT, x, W, bias, xwbT);
    prep_kernel<<<dim3(8512), dim3(256), 0, stream>>>(HT, HTe, rs_e, rd_n);
    v2e_k<<<dim3(8 * (E_ / MT)), dim3(256), 0, stream>>>(HT, xwbT, rs_e, ebfT);
    e2v_k<<<dim3(8 * (N_ / MT)), dim3(256), 0, stream>>>(HTe, ebfT, rd_n, out);
}

// Round 12
// 466.083 us; speedup vs baseline: 1.0246x; 1.0246x over previous
//
#include <hip/hip_runtime.h>
#include <stdint.h>

// Problem constants
constexpr int B_ = 8, N_ = 4096, E_ = 2048, C_ = 128;
constexpr int KT  = 32;    // K per MFMA step
constexpr int MT  = 64;    // M rows per block (4 x 16-row groups, all owned by every wave)
constexpr int NJW = 4;     // col-tiles per wave (2x2 split: k-half x col-half)
constexpr int LRP = 65;    // reduction LDS row stride (floats, +1 pad)

typedef short bf16x8 __attribute__((ext_vector_type(8)));
typedef float f32x4  __attribute__((ext_vector_type(4)));
typedef unsigned int u32x4 __attribute__((ext_vector_type(4)));

__device__ inline uint16_t bf16_rne(float f) {
    uint32_t u = __builtin_bit_cast(uint32_t, f);
    return (uint16_t)((u + 0x7FFFu + ((u >> 16) & 1u)) >> 16);
}

constexpr size_t BIT_B = (size_t)(N_ / 32) * E_;       // 262144 dwords per batch
constexpr size_t HT_E  = (size_t)B_ * BIT_B;           // 2M dwords = 8 MB
constexpr size_t WT_E  = (size_t)C_ * C_;              // 16384 bf16
constexpr size_t EBF_E = (size_t)B_ * C_ * E_;         // 2M bf16 = 4 MB
constexpr size_t RS_E  = (size_t)B_ * E_;              // 16K floats
constexpr size_t RD_E  = (size_t)B_ * N_;              // 32K floats

// ---------------------------------------------------------------------------
// pack: H (fp32 0/1) -> HT[b][n/32][e] (bit = n%32) AND, via in-register
// 32x ballot transpose, HTe[b][e/32][n] (bit = e%32). HBM-bound (268 MB read).
// ---------------------------------------------------------------------------
__global__ void pack_kernel(const float* __restrict__ H, uint32_t* __restrict__ HT,
                            uint32_t* __restrict__ HTe) {
    const int t  = threadIdx.x;
    const int eg = blockIdx.x & 7;
    const int ng = (blockIdx.x >> 3) & 127;
    const int b  = blockIdx.x >> 10;
    const int e  = eg * 256 + t;
    const float* hp = H + ((size_t)b * N_ + ng * 32) * E_ + e;
    uint32_t w = 0;
#pragma unroll
    for (int i = 0; i < 32; ++i) w |= (hp[(size_t)i * E_] > 0.5f) ? (1u << i) : 0u;
    HT[((size_t)b * (N_ / 32) + ng) * E_ + e] = w;

    // e-packed transpose: wave (64 e's) x 32 n-bits -> 64 HTe words
    const int lane  = t & 63;
    const int ebase = eg * 256 + (t >> 6) * 64;
    uint32_t val = 0;
#pragma unroll
    for (int i = 0; i < 32; ++i) {
        unsigned long long m = __ballot((w >> i) & 1u);
        uint32_t half = (lane < 32) ? (uint32_t)m : (uint32_t)(m >> 32);
        if ((lane & 31) == i) val = half;
    }
    HTe[((size_t)b * (E_ / 32) + (ebase >> 5) + (lane >> 5)) * N_ + ng * 32 + (lane & 31)] = val;
}

// ---------------------------------------------------------------------------
// prep: rd_n = 0.5/deg(n) (popc over HTe cols), rs_e = 0.5/deg(e) (popc over
// HT cols), WTb = bf16(W^T). The 0.5 compensates bit-value 2.0 in the GEMMs.
// ---------------------------------------------------------------------------
__global__ void prep_kernel(const float* __restrict__ W, const uint32_t* __restrict__ HT,
                            const uint32_t* __restrict__ HTe, uint16_t* __restrict__ WTb,
                            float* __restrict__ rs_e, float* __restrict__ rd_n) {
    const int blk = blockIdx.x, t = threadIdx.x;
    if (blk < 128) {                              // rd_n: 32768 = (b, n)
        const int i = blk * 256 + t;
        const int b = i >> 12, n = i & 4095;
        const uint32_t* p = HTe + (size_t)b * BIT_B + n;
        int s = 0;
#pragma unroll 1
        for (int ew = 0; ew < E_ / 32; ++ew) s += __popc(p[(size_t)ew * N_]);
        rd_n[i] = (s > 0) ? 0.5f / (float)s : 0.f;
    } else if (blk < 192) {                       // rs_e: 16384 = (b, e)
        const int i = (blk - 128) * 256 + t;
        const int b = i >> 11, e = i & 2047;
        const uint32_t* p = HT + (size_t)b * BIT_B + e;
        int s = 0;
#pragma unroll 1
        for (int ng = 0; ng < N_ / 32; ++ng) s += __popc(p[(size_t)ng * E_]);
        rs_e[i] = (s > 0) ? 0.5f / (float)s : 0.f;
    } else if (blk < 256) {                       // WTb: 16384 = c*128+k
        const int i = (blk - 192) * 256 + t;
        const int c = i >> 7, k = i & 127;
        WTb[i] = bf16_rne(W[k * C_ + c]);
    }
}

// ---------------------------------------------------------------------------
// 2x2-SPLIT MFMA GEMM: wave = (k-half, col-half). Each wave owns 4 col-tiles
// and K/2 -> expanded A-fragments amortize over 16 MFMAs/step (the N-split's
// 4x A-expansion inflation undone) while B stays in a 4-deep named-register
// pipeline (R6 correctness model: compiler-scoreboarded waits, no LDS, no
// manual vmcnt). Cross-wave k-half reduction = ONE barrier via 33 KB LDS
// (waves 1,3 store; waves 0,2 add + write disjoint col-halves).
//  MODE 0 (fc) : A = x fp32,        B = WTb,  out bf16 C^T xwbT (+bias)
//  MODE 1 (v2e): A = HT bits (2.0), B = xwbT, out bf16 C^T ebfT (x 0.5/s_e)
//  MODE 2 (e2v): A = HTe bits(2.0), B = ebfT, out fp32 row-major (x 0.5/d_n)
// ---------------------------------------------------------------------------

#define LOADA(S, k0_) do {                                                            \
    if constexpr (MODE == 0) {                                                        \
        _Pragma("unroll")                                                             \
        for (int g = 0; g < NG; ++g) {                                                \
            const float* ap = Ax + ((size_t)batch * N_ + m0 + g * 16 + l15) * C_ + (k0_) + quad * 8; \
            const float4 f0 = *(const float4*)ap;                                     \
            const float4 f1 = *(const float4*)(ap + 4);                               \
            af##S[g*8+0]=f0.x; af##S[g*8+1]=f0.y; af##S[g*8+2]=f0.z; af##S[g*8+3]=f0.w; \
            af##S[g*8+4]=f1.x; af##S[g*8+5]=f1.y; af##S[g*8+6]=f1.z; af##S[g*8+7]=f1.w; \
        }                                                                             \
    } else {                                                                          \
        const uint32_t* p = Hp + (size_t)((k0_) >> 5) * RL + m0 + l15;                \
        _Pragma("unroll")                                                             \
        for (int g = 0; g < NG; ++g) aw##S[g] = p[g * 16];                            \
    } } while (0)

#define LOADB(S, k0_) do {                                                            \
    _Pragma("unroll")                                                                 \
    for (int j2 = 0; j2 < NJW; ++j2)                                                  \
        bq##S[j2] = *(const bf16x8*)&Bp[(size_t)((jw + j2) * 16 + l15) * K + (k0_) + quad * 8]; \
    } while (0)

// bit->bf16(2.0) fast expansion: nibble * 0x204081 spreads bit i to byte i;
// &0x01010101 <<6 makes bytes 0x40*bit; v_perm zero-interleaves -> packed
// bf16 pairs. 12 VALU per 8 elements (vs ~64 for the naive path, R7 ablation).
#define MKFRAGS(S, A)                                                                 \
    bf16x8 A[NG];                                                                     \
    do {                                                                              \
    if constexpr (MODE == 0) {                                                        \
        _Pragma("unroll")                                                             \
        for (int g = 0; g < NG; ++g)                                                  \
            { _Pragma("unroll")                                                       \
              for (int jj = 0; jj < 8; ++jj) A[g][jj] = (short)bf16_rne(af##S[g*8+jj]); } \
    } else {                                                                          \
        const int qs = quad * 8;                                                      \
        _Pragma("unroll")                                                             \
        for (int g = 0; g < NG; ++g) {                                                \
            const uint32_t wv = aw##S[g];                                             \
            const uint32_t nb0 = (wv >> qs) & 0xFu;                                   \
            const uint32_t nb1 = (wv >> (qs + 4)) & 0xFu;                             \
            const uint32_t s0m = ((nb0 * 0x204081u) & 0x01010101u) << 6;              \
            const uint32_t s1m = ((nb1 * 0x204081u) & 0x01010101u) << 6;              \
            u32x4 qq = { __builtin_amdgcn_perm(s0m, 0u, 0x05000400u),                 \
                         __builtin_amdgcn_perm(s0m, 0u, 0x07000600u),                 \
                         __builtin_amdgcn_perm(s1m, 0u, 0x05000400u),                 \
                         __builtin_amdgcn_perm(s1m, 0u, 0x07000600u) };               \
            A[g] = __builtin_bit_cast(bf16x8, qq);                                    \
        }                                                                             \
    } } while (0)

template <int MODE>
__device__ __attribute__((always_inline))
void gemm_body(const float* __restrict__ Ax, const uint32_t* __restrict__ bits,
               const uint16_t* __restrict__ Btb, const float* __restrict__ bias,
               const float* __restrict__ rcp, uint16_t* __restrict__ outT,
               float* __restrict__ outF) {
    constexpr int K   = (MODE == 0) ? C_ : (MODE == 1) ? N_ : E_;
    constexpr int KH  = K / 2;                    // per-wave K half
    constexpr int SW  = KH / KT;                  // 2 / 64 / 32 steps
    constexpr int OLD = (MODE == 0) ? N_ : E_;
    constexpr int RL  = (MODE == 1) ? E_ : N_;    // bit-row stride == rcp stride
    constexpr int NG  = MT / 16;                  // 4 m-groups per wave
    static_assert(SW == 2 || (SW >= 4 && SW % 4 == 0), "pipeline shape");

    __shared__ float R[2 * 64 * LRP];             // two 64x64(+pad) k-half partials

    const int t = threadIdx.x, wave = t >> 6, lane = t & 63;
    const int l15 = lane & 15, quad = lane >> 4;
    const int kh = wave & 1, jg = wave >> 1;      // k-half, col-half
    const int jw = jg * NJW;                      // first owned col-tile
    const int kwv = kh * KH;
    const int batch = blockIdx.x & 7;             // batch -> XCD: panel stays in one L2
    const int m0 = (blockIdx.x >> 3) * MT;

    const uint16_t* Bp = Btb + (MODE == 0 ? (size_t)0 : (size_t)batch * C_ * K);
    const uint32_t* Hp = bits + (size_t)batch * BIT_B;

    f32x4 acc[NG * NJW];
    // all four pipeline stages declared for every MODE (names must exist even
    // in constexpr-discarded branches; unused arrays cost nothing)
    float    af0[NG * 8], af1[NG * 8], af2[NG * 8], af3[NG * 8];
    uint32_t aw0[NG], aw1[NG], aw2[NG], aw3[NG];
    bf16x8   bq0[NJW], bq1[NJW], bq2[NJW], bq3[NJW];

    auto mfma_all = [&](const bf16x8 (&A)[NG], const bf16x8 (&bv)[NJW])
        __attribute__((always_inline)) {
#pragma unroll
        for (int j2 = 0; j2 < NJW; ++j2)
#pragma unroll
            for (int g = 0; g < NG; ++g)
                acc[g * NJW + j2] = __builtin_amdgcn_mfma_f32_16x16x32_bf16(A[g], bv[j2], acc[g * NJW + j2], 0, 0, 0);
    };

#pragma unroll
    for (int i = 0; i < NG * NJW; ++i) acc[i] = (f32x4){0.f, 0.f, 0.f, 0.f};

    if constexpr (SW >= 4) {
        // 4-deep register pipeline (3-step prefetch lead)
        LOADA(0, kwv);          LOADB(0, kwv);
        LOADA(1, kwv + KT);     LOADB(1, kwv + KT);
        LOADA(2, kwv + 2 * KT); LOADB(2, kwv + 2 * KT);
        LOADA(3, kwv + 3 * KT); LOADB(3, kwv + 3 * KT);
#pragma unroll 1
        for (int s = 0; s < SW - 4; s += 4) {
            { MKFRAGS(0, A0); mfma_all(A0, bq0); LOADA(0, kwv + (s + 4) * KT); LOADB(0, kwv + (s + 4) * KT); }
            { MKFRAGS(1, A1); mfma_all(A1, bq1); LOADA(1, kwv + (s + 5) * KT); LOADB(1, kwv + (s + 5) * KT); }
            { MKFRAGS(2, A2); mfma_all(A2, bq2); LOADA(2, kwv + (s + 6) * KT); LOADB(2, kwv + (s + 6) * KT); }
            { MKFRAGS(3, A3); mfma_all(A3, bq3); LOADA(3, kwv + (s + 7) * KT); LOADB(3, kwv + (s + 7) * KT); }
        }
        { MKFRAGS(0, A0); mfma_all(A0, bq0); }
        { MKFRAGS(1, A1); mfma_all(A1, bq1); }
        { MKFRAGS(2, A2); mfma_all(A2, bq2); }
        { MKFRAGS(3, A3); mfma_all(A3, bq3); }
    } else {
        // fc: SW==2, simple 2-deep
        LOADA(0, kwv);      LOADB(0, kwv);
        LOADA(1, kwv + KT); LOADB(1, kwv + KT);
        { MKFRAGS(0, A0); mfma_all(A0, bq0); }
        { MKFRAGS(1, A1); mfma_all(A1, bq1); }
    }

    // ---- k-half reduction: ONE barrier ----
    const int rbase = jg * 64 * LRP;
    if (kh == 1) {
#pragma unroll
        for (int g = 0; g < NG; ++g)
#pragma unroll
            for (int j2 = 0; j2 < NJW; ++j2)
#pragma unroll
                for (int r = 0; r < 4; ++r)
                    R[rbase + (g * 16 + quad * 4 + r) * LRP + j2 * 16 + l15] = acc[g * NJW + j2][r];
    }
    __syncthreads();
    if (kh != 0) return;
#pragma unroll
    for (int g = 0; g < NG; ++g)
#pragma unroll
        for (int j2 = 0; j2 < NJW; ++j2)
#pragma unroll
            for (int r = 0; r < 4; ++r)
                acc[g * NJW + j2][r] += R[rbase + (g * 16 + quad * 4 + r) * LRP + j2 * 16 + l15];

    // ---- epilogue (waves 0 and 2: disjoint col-halves) ----
    float mul[NG][4];
    if constexpr (MODE != 0) {
#pragma unroll
        for (int g = 0; g < NG; ++g) {
            const float4 rv = *(const float4*)&rcp[(size_t)batch * RL + m0 + g * 16 + quad * 4];
            mul[g][0] = rv.x; mul[g][1] = rv.y; mul[g][2] = rv.z; mul[g][3] = rv.w;
        }
    }
#pragma unroll
    for (int g = 0; g < NG; ++g) {
        const int row = m0 + g * 16 + quad * 4;
        if constexpr (MODE == 2) {
            float* op = outF + ((size_t)batch * N_ + row) * C_;
#pragma unroll
            for (int j2 = 0; j2 < NJW; ++j2) {
                const int c = (jw + j2) * 16 + l15;
#pragma unroll
                for (int r = 0; r < 4; ++r) op[(size_t)r * C_ + c] = acc[g * NJW + j2][r] * mul[g][r];
            }
        } else {
#pragma unroll
            for (int j2 = 0; j2 < NJW; ++j2) {
                const int c = (jw + j2) * 16 + l15;
                float v0, v1, v2, v3;
                if constexpr (MODE == 0) {
                    float bb = bias[c];
                    v0 = acc[g * NJW + j2][0] + bb; v1 = acc[g * NJW + j2][1] + bb;
                    v2 = acc[g * NJW + j2][2] + bb; v3 = acc[g * NJW + j2][3] + bb;
                } else {
                    v0 = acc[g * NJW + j2][0] * mul[g][0]; v1 = acc[g * NJW + j2][1] * mul[g][1];
                    v2 = acc[g * NJW + j2][2] * mul[g][2]; v3 = acc[g * NJW + j2][3] * mul[g][3];
                }
                uint32_t q0 = (uint32_t)bf16_rne(v0) | ((uint32_t)bf16_rne(v1) << 16);
                uint32_t q1 = (uint32_t)bf16_rne(v2) | ((uint32_t)bf16_rne(v3) << 16);
                uint16_t* op = outT + ((size_t)batch * C_ + c) * OLD + row;
                *(uint2*)op = make_uint2(q0, q1);
            }
        }
    }
}

// Named wrappers -> attributable rocprof rows
__global__ __launch_bounds__(256, 2)
void fc_k(const float* __restrict__ Ax, const uint16_t* __restrict__ Btb,
          const float* __restrict__ bias, uint16_t* __restrict__ outT) {
    gemm_body<0>(Ax, nullptr, Btb, bias, nullptr, outT, nullptr);
}
__global__ __launch_bounds__(256, 2)
void v2e_k(const uint32_t* __restrict__ HT, const uint16_t* __restrict__ Btb,
           const float* __restrict__ rcp, uint16_t* __restrict__ outT) {
    gemm_body<1>(nullptr, HT, Btb, nullptr, rcp, outT, nullptr);
}
__global__ __launch_bounds__(256, 2)
void e2v_k(const uint32_t* __restrict__ HTe, const uint16_t* __restrict__ Btb,
           const float* __restrict__ rcp, float* __restrict__ outF) {
    gemm_body<2>(nullptr, HTe, Btb, nullptr, rcp, nullptr, outF);
}

// ---------------------------------------------------------------------------
extern "C" void kernel_launch(void* const* d_in, const int* in_sizes, int n_in,
                              void* d_out, int out_size, void* d_ws, size_t ws_size,
                              hipStream_t stream) {
    const float* x    = (const float*)d_in[0];   // [8,4096,128]
    const float* H    = (const float*)d_in[1];   // [8,4096,2048]
    const float* W    = (const float*)d_in[2];   // [128,128]
    const float* bias = (const float*)d_in[3];   // [128]
    float* out = (float*)d_out;                  // [8,4096,128]

    // ws (~20.3 MB): HT 8MB | HTe 8MB | WTb 32KB | ebfT 4MB | rs_e 64KB | rd_n 128KB
    uint32_t* HT   = (uint32_t*)d_ws;
    uint32_t* HTe  = HT + HT_E;
    uint16_t* WTb  = (uint16_t*)(HTe + HT_E);
    uint16_t* ebfT = WTb + WT_E;
    float*    rs_e = (float*)(ebfT + EBF_E);
    float*    rd_n = rs_e + RS_E;
    uint16_t* xwbT = (uint16_t*)d_out;           // d_out is dead scratch until e2v

    pack_kernel<<<dim3(8192), dim3(256), 0, stream>>>(H, HT, HTe);
    prep_kernel<<<dim3(256), dim3(256), 0, stream>>>(W, HT, HTe, WTb, rs_e, rd_n);
    fc_k <<<dim3(8 * (N_ / MT)), dim3(256), 0, stream>>>(x, WTb, bias, xwbT);
    v2e_k<<<dim3(8 * (E_ / MT)), dim3(256), 0, stream>>>(HT, xwbT, rs_e, ebfT);
    e2v_k<<<dim3(8 * (N_ / MT)), dim3(256), 0, stream>>>(HTe, ebfT, rd_n, out);
}